// Round 1
// baseline (915.008 us; speedup 1.0000x reference)
//
#include <hip/hip_runtime.h>

#define HDIM 256
#define LNEPS 1e-5f

typedef float f32x4 __attribute__((ext_vector_type(4)));
typedef short bf16x8 __attribute__((ext_vector_type(8)));

static __device__ __forceinline__ unsigned short f2b(float f) {
  union { float f; unsigned u; } v; v.f = f;
  return (unsigned short)((v.u + 0x7fffu + ((v.u >> 16) & 1u)) >> 16);
}
static __device__ __forceinline__ unsigned pk2(float lo, float hi) {
  return (unsigned)f2b(lo) | ((unsigned)f2b(hi) << 16);
}

// ---------------- transpose + bf16 convert: in[K][N] -> out[N][K] ----------------
__global__ void cvtw_kernel(const float* __restrict__ in, unsigned short* __restrict__ out,
                            int K, int N) {
  int idx = blockIdx.x * 256 + threadIdx.x;
  if (idx >= K * N) return;
  int k = idx / N, n = idx - k * N;
  out[(size_t)n * K + k] = f2b(in[idx]);
}

// ---------------- per-graph counts ----------------
__global__ void count_kernel(const int* __restrict__ node_gid, const int* __restrict__ bond_gid,
                             int* cnt_node, int* cnt_bond, int N, int E) {
  int i = blockIdx.x * 256 + threadIdx.x;
  if (i < N) atomicAdd(&cnt_node[node_gid[i]], 1);
  if (i < E) atomicAdd(&cnt_bond[bond_gid[i]], 1);
}

__global__ void factor_kernel(const int* __restrict__ cnt_node, const int* __restrict__ cnt_bond,
                              float* fac_node, float* fac_bond, float* recip_node, int G) {
  int g = blockIdx.x * 256 + threadIdx.x;
  if (g >= G) return;
  float cn = fmaxf((float)cnt_node[g], 1.f);
  float cb = fmaxf((float)cnt_bond[g], 1.f);
  fac_node[g] = rsqrtf(cn);
  fac_bond[g] = rsqrtf(cb);
  recip_node[g] = 1.f / cn;
}

// ---------------- CSR build ----------------
__global__ void deg_kernel(const int* __restrict__ dst, int* __restrict__ deg, int n) {
  int i = blockIdx.x * 256 + threadIdx.x;
  if (i < n) atomicAdd(&deg[dst[i]], 1);
}

__global__ void scan1_kernel(const int* __restrict__ deg, int* __restrict__ excl,
                             int* __restrict__ bsum, int n) {
  int t = threadIdx.x;
  int i = blockIdx.x * 256 + t;
  int v = (i < n) ? deg[i] : 0;
  int lane = t & 63, w = t >> 6;
  int s = v;
#pragma unroll
  for (int d = 1; d < 64; d <<= 1) {
    int u = __shfl_up(s, d);
    if (lane >= d) s += u;
  }
  __shared__ int wsum[4];
  if (lane == 63) wsum[w] = s;
  __syncthreads();
  int base = 0;
  for (int ww = 0; ww < w; ++ww) base += wsum[ww];
  if (i < n) excl[i] = base + s - v;
  if (t == 255) bsum[blockIdx.x] = base + s;
}

__global__ void scan2_kernel(int* __restrict__ bsum, int nb) {
  int t = threadIdx.x;  // 1024 threads
  int v = (t < nb) ? bsum[t] : 0;
  int lane = t & 63, w = t >> 6;
  int s = v;
#pragma unroll
  for (int d = 1; d < 64; d <<= 1) {
    int u = __shfl_up(s, d);
    if (lane >= d) s += u;
  }
  __shared__ int wsum[16];
  if (lane == 63) wsum[w] = s;
  __syncthreads();
  int base = 0;
  for (int ww = 0; ww < w; ++ww) base += wsum[ww];
  if (t < nb) bsum[t] = base + s - v;
}

__global__ void scan3_kernel(int* __restrict__ excl, const int* __restrict__ bsum, int n) {
  int i = blockIdx.x * 256 + threadIdx.x;
  if (i < n) excl[i] += bsum[blockIdx.x];
}

__global__ void fill_kernel(const int* __restrict__ dst, const int* __restrict__ off,
                            int* __restrict__ cursor, int* __restrict__ csr, int n) {
  int i = blockIdx.x * 256 + threadIdx.x;
  if (i >= n) return;
  int d = dst[i];
  int p = atomicAdd(&cursor[d], 1);
  csr[off[d] + p] = i;
}

// ---------------- gather: agg_e[d] = (Σ rbf_a)@W + cnt·b + Σ edge_hidden[src_a] ----------------
__global__ __launch_bounds__(256) void angle_gather_kernel(
    const float* __restrict__ bond_angle, const int* __restrict__ ba_src,
    const float* __restrict__ edge_hidden,
    const int* __restrict__ off, const int* __restrict__ deg, const int* __restrict__ csr,
    const float* __restrict__ rbf_w, const float* __restrict__ rbf_b,
    float* __restrict__ agg_e, int E) {
  int w = threadIdx.x >> 6, lane = threadIdx.x & 63;
  int d = blockIdx.x * 4 + w;
  if (d >= E) return;
  int c4 = lane * 4;
  int start = off[d], cnt = deg[d];
  f32x4 acc = (f32x4)0.f;
  float rbfs = 0.f;
  float cc = 0.1f * (float)(lane & 31);
  for (int i = 0; i < cnt; ++i) {
    int a = csr[start + i];
    float av = bond_angle[a];
    if (lane < 32) {
      float dd = av - cc;
      rbfs += __expf(-10.f * dd * dd);
    }
    int s = ba_src[a];
    acc += *(const f32x4*)&edge_hidden[(size_t)s * HDIM + c4];
  }
#pragma unroll
  for (int k = 0; k < 32; ++k) {
    float rv = __shfl(rbfs, k);
    f32x4 wv = *(const f32x4*)&rbf_w[k * HDIM + c4];
    acc[0] += rv * wv[0]; acc[1] += rv * wv[1];
    acc[2] += rv * wv[2]; acc[3] += rv * wv[3];
  }
  f32x4 bv = *(const f32x4*)&rbf_b[c4];
  float fc = (float)cnt;
  acc[0] += fc * bv[0]; acc[1] += fc * bv[1];
  acc[2] += fc * bv[2]; acc[3] += fc * bv[3];
  *(f32x4*)&agg_e[(size_t)d * HDIM + c4] = acc;
}

// ---------------- gather: agg_n[d] = Σ (edge_out[e] + node_hidden[src_e]) ----------------
__global__ __launch_bounds__(256) void node_gather_kernel(
    const float* __restrict__ node_hidden, const float* __restrict__ edge_out,
    const int* __restrict__ ab_src,
    const int* __restrict__ off, const int* __restrict__ deg, const int* __restrict__ csr,
    float* __restrict__ agg_n, int N) {
  int w = threadIdx.x >> 6, lane = threadIdx.x & 63;
  int d = blockIdx.x * 4 + w;
  if (d >= N) return;
  int c4 = lane * 4;
  int start = off[d], cnt = deg[d];
  f32x4 acc = (f32x4)0.f;
  for (int i = 0; i < cnt; ++i) {
    int e = csr[start + i];
    int s = ab_src[e];
    f32x4 a = *(const f32x4*)&edge_out[(size_t)e * HDIM + c4];
    f32x4 b = *(const f32x4*)&node_hidden[(size_t)s * HDIM + c4];
    acc += a;
    acc += b;
  }
  *(f32x4*)&agg_n[(size_t)d * HDIM + c4] = acc;
}

// ---------------- fused MLP + LayerNorm + graph_normal + residual (+pool) ----------------
// 64 rows/block, 512 threads (8 waves).
// GEMM1 SWAPPED (H1^T = W1^T @ X^T), H1 processed in FOUR 128-col quarters (16KB buffer).
// Epilogue (b2 + LN + graph_normal + residual + pool) entirely from registers:
// per-row stats via shfl_xor over the 16-lane fragment groups + 4KB cross-wave LDS reduce.
// LDS total 54272 B -> 3 blocks/CU (24 waves) vs previous 66560 B (2 blocks).
template <int POOL>
__global__ __launch_bounds__(512, 6) void mlp_kernel(
    const float* agg_in, float* out_rows,  // may alias (in-place per-block)
    const float* __restrict__ residual, const int* __restrict__ gid,
    const float* __restrict__ gfactor,
    const unsigned short* __restrict__ w1t, const float* __restrict__ b1,
    const unsigned short* __restrict__ w2t, const float* __restrict__ b2,
    const float* __restrict__ ln_g, const float* __restrict__ ln_b,
    float* pool_out, int M) {
  __shared__ __align__(16) char smem[54272];
  char* Xb = smem;                              // bf16 [64][256] swizzled, 32KB
  char* Hb = smem + 32768;                      // bf16 [64][128] (one quarter), 16KB
  float* psumA = (float*)(smem + 49152);        // [64][8] row partial sums, 2KB
  float* psumB = (float*)(smem + 51200);        // [64][8] row partial sumsq, 2KB
  float* fstat = (float*)(smem + 53248);        // [64][2] mean/rstd
  float* gfs = (float*)(smem + 53760);          // [64]
  int* gid_s = (int*)(smem + 54016);            // [64]

  int t = threadIdx.x;
  int row0 = blockIdx.x * 64;
  int w = t >> 6, lane = t & 63;
  int l15 = lane & 15, lg = lane >> 4;

  // ---- stage X: f32 -> bf16 LDS (swizzled); graph factors ----
  {
    int row = t >> 3;
    int c0 = (t & 7) * 32;
    int gr = row0 + row; if (gr >= M) gr = M - 1;
    const float* src = agg_in + (size_t)gr * HDIM + c0;
#pragma unroll
    for (int i = 0; i < 4; ++i) {
      f32x4 a = *(const f32x4*)(src + i * 8);
      f32x4 b = *(const f32x4*)(src + i * 8 + 4);
      int byte = (row * 512 + (c0 + i * 8) * 2) ^ ((row & 7) << 4);
      *(uint4*)(Xb + byte) =
          make_uint4(pk2(a[0], a[1]), pk2(a[2], a[3]), pk2(b[0], b[1]), pk2(b[2], b[3]));
    }
    if (t < 64) {
      int r = row0 + t;
      int g = (r < M) ? gid[r] : 0;
      gid_s[t] = g;
      gfs[t] = gfactor[g];
    }
  }
  __syncthreads();

  f32x4 acc2[4][2];  // [mt][nf] : row m = mt*16 + lg*4 + jr ; col n2 = w*32 + nf*16 + l15
#pragma unroll
  for (int mt = 0; mt < 4; ++mt)
#pragma unroll
    for (int nf = 0; nf < 2; ++nf) acc2[mt][nf] = (f32x4)0.f;

  for (int h = 0; h < 4; ++h) {
    // ---- GEMM1 (swapped): D[n1][m]; wave's n1 tile = h*128 + w*16 ----
    f32x4 acc1[4];
#pragma unroll
    for (int mt = 0; mt < 4; ++mt) acc1[mt] = (f32x4)0.f;

    const unsigned short* a1p = w1t + (size_t)(h * 128 + w * 16 + l15) * 256 + lg * 8;
#pragma unroll
    for (int kk = 0; kk < 8; ++kk) {
      bf16x8 afr = *(const bf16x8*)(a1p + kk * 32);
#pragma unroll
      for (int mt = 0; mt < 4; ++mt) {
        int m = mt * 16 + l15;
        int byte = (m * 512 + kk * 64 + lg * 16) ^ ((m & 7) << 4);
        bf16x8 xfr = *(const bf16x8*)(Xb + byte);
        acc1[mt] = __builtin_amdgcn_mfma_f32_16x16x32_bf16(afr, xfr, acc1[mt], 0, 0, 0);
      }
    }

    // ---- bias + relu + packed H1 store: H1[m][n1q], n1q = w*16 + lg*4 + jr ----
    {
      f32x4 b1v = *(const f32x4*)&b1[h * 128 + w * 16 + lg * 4];
#pragma unroll
      for (int mt = 0; mt < 4; ++mt) {
        f32x4 v = acc1[mt] + b1v;
        v[0] = fmaxf(v[0], 0.f); v[1] = fmaxf(v[1], 0.f);
        v[2] = fmaxf(v[2], 0.f); v[3] = fmaxf(v[3], 0.f);
        int m = mt * 16 + l15;
        int byte = (m * 256 + w * 32 + lg * 8) ^ ((m & 7) << 4);
        *(uint2*)(Hb + byte) = make_uint2(pk2(v[0], v[1]), pk2(v[2], v[3]));
      }
    }
    __syncthreads();

    // ---- GEMM2 partial: A = H1 rows (LDS quarter), B = w2t cols (L2) ----
    const unsigned short* w2p = w2t + (size_t)(w * 32 + l15) * 512 + h * 128 + lg * 8;
#pragma unroll
    for (int kk = 0; kk < 4; ++kk) {
      bf16x8 wfr0 = *(const bf16x8*)(w2p + kk * 32);
      bf16x8 wfr1 = *(const bf16x8*)(w2p + 16 * 512 + kk * 32);
#pragma unroll
      for (int mt = 0; mt < 4; ++mt) {
        int m = mt * 16 + l15;
        int byte = (m * 256 + kk * 64 + lg * 16) ^ ((m & 7) << 4);
        bf16x8 hfr = *(const bf16x8*)(Hb + byte);
        acc2[mt][0] = __builtin_amdgcn_mfma_f32_16x16x32_bf16(hfr, wfr0, acc2[mt][0], 0, 0, 0);
        acc2[mt][1] = __builtin_amdgcn_mfma_f32_16x16x32_bf16(hfr, wfr1, acc2[mt][1], 0, 0, 0);
      }
    }
    if (h < 3) __syncthreads();  // protect Hb before next quarter's writes
  }

  // ---- LayerNorm stats from registers: reduce 32 cols/wave via shfl, 8 waves via LDS ----
  int c0 = w * 32 + l15;
  float b2v0 = b2[c0], b2v1 = b2[c0 + 16];
#pragma unroll
  for (int mt = 0; mt < 4; ++mt) {
#pragma unroll
    for (int jr = 0; jr < 4; ++jr) {
      float v0 = acc2[mt][0][jr] + b2v0;
      float v1 = acc2[mt][1][jr] + b2v1;
      float s = v0 + v1, ss = v0 * v0 + v1 * v1;
      s += __shfl_xor(s, 1); ss += __shfl_xor(ss, 1);
      s += __shfl_xor(s, 2); ss += __shfl_xor(ss, 2);
      s += __shfl_xor(s, 4); ss += __shfl_xor(ss, 4);
      s += __shfl_xor(s, 8); ss += __shfl_xor(ss, 8);
      if (l15 == 0) {
        int r = mt * 16 + lg * 4 + jr;
        psumA[r * 8 + w] = s;
        psumB[r * 8 + w] = ss;
      }
    }
  }
  __syncthreads();
  if (t < 64) {
    float s = 0.f, ss = 0.f;
#pragma unroll
    for (int i = 0; i < 8; ++i) { s += psumA[t * 8 + i]; ss += psumB[t * 8 + i]; }
    float mean = s * (1.f / 256.f);
    float var = ss * (1.f / 256.f) - mean * mean;
    fstat[t * 2] = mean;
    fstat[t * 2 + 1] = rsqrtf(var + LNEPS);
  }
  __syncthreads();

  // ---- finalize from registers: LN affine, graph_normal, residual, store (+pool) ----
  {
    float g0 = ln_g[c0], g1 = ln_g[c0 + 16];
    float be0 = ln_b[c0], be1 = ln_b[c0 + 16];
    int curg = -1;
    float p0 = 0.f, p1 = 0.f;
#pragma unroll
    for (int mt = 0; mt < 4; ++mt) {
#pragma unroll
      for (int jr = 0; jr < 4; ++jr) {
        int r = mt * 16 + lg * 4 + jr;
        int gr = row0 + r;
        if (gr < M) {
          float mean = fstat[r * 2], rstd = fstat[r * 2 + 1];
          float gf = gfs[r];
          float v0 = ((acc2[mt][0][jr] + b2v0 - mean) * rstd * g0 + be0) * gf
                   + residual[(size_t)gr * HDIM + c0];
          float v1 = ((acc2[mt][1][jr] + b2v1 - mean) * rstd * g1 + be1) * gf
                   + residual[(size_t)gr * HDIM + c0 + 16];
          out_rows[(size_t)gr * HDIM + c0] = v0;
          out_rows[(size_t)gr * HDIM + c0 + 16] = v1;
          if (POOL) {
            int g = gid_s[r];
            if (g != curg) {
              if (curg >= 0) {
                atomicAdd(&pool_out[(size_t)curg * HDIM + c0], p0);
                atomicAdd(&pool_out[(size_t)curg * HDIM + c0 + 16], p1);
              }
              curg = g; p0 = 0.f; p1 = 0.f;
            }
            p0 += v0; p1 += v1;
          }
        }
      }
    }
    if (POOL && curg >= 0) {
      atomicAdd(&pool_out[(size_t)curg * HDIM + c0], p0);
      atomicAdd(&pool_out[(size_t)curg * HDIM + c0 + 16], p1);
    }
  }
}

// ---------------- pooled sums -> means ----------------
__global__ void pooldiv_kernel(float* out_graph, const float* __restrict__ recip_node) {
  int g = blockIdx.x, t = threadIdx.x;
  out_graph[(size_t)g * HDIM + t] *= recip_node[g];
}

extern "C" void kernel_launch(void* const* d_in, const int* in_sizes, int n_in,
                              void* d_out, int out_size, void* d_ws, size_t ws_size,
                              hipStream_t stream) {
  const float* node_hidden = (const float*)d_in[0];
  const float* edge_hidden = (const float*)d_in[1];
  const float* bond_angle = (const float*)d_in[2];
  const int* ab_src = (const int*)d_in[3];
  const int* ab_dst = (const int*)d_in[4];
  const int* ba_src = (const int*)d_in[5];
  const int* ba_dst = (const int*)d_in[6];
  const int* node_gid = (const int*)d_in[7];
  const int* bond_gid = (const int*)d_in[8];
  const float* rbf_w = (const float*)d_in[10];
  const float* rbf_b = (const float*)d_in[11];
  const float* ba_w1 = (const float*)d_in[12];
  const float* ba_b1 = (const float*)d_in[13];
  const float* ba_w2 = (const float*)d_in[14];
  const float* ba_b2 = (const float*)d_in[15];
  const float* ba_ln_g = (const float*)d_in[16];
  const float* ba_ln_b = (const float*)d_in[17];
  const float* ab_w1 = (const float*)d_in[18];
  const float* ab_b1 = (const float*)d_in[19];
  const float* ab_w2 = (const float*)d_in[20];
  const float* ab_b2 = (const float*)d_in[21];
  const float* ab_ln_g = (const float*)d_in[22];
  const float* ab_ln_b = (const float*)d_in[23];

  int N = in_sizes[0] / HDIM;
  int E = in_sizes[1] / HDIM;
  int A = in_sizes[2];
  int G = out_size / HDIM - N - E;

  float* out_node = (float*)d_out;
  float* out_edge = out_node + (size_t)N * HDIM;
  float* out_graph = out_edge + (size_t)E * HDIM;

  // ---- workspace layout ----
  char* ws = (char*)d_ws;
  int* cnt_node = (int*)ws;                    // G   (zeroed)
  int* cnt_bond = cnt_node + G;                // G   (zeroed)
  int* deg_e = cnt_bond + G;                   // E   (zeroed)
  int* cur_e = deg_e + E;                      // E   (zeroed)
  int* deg_n = cur_e + E;                      // N   (zeroed)
  int* cur_n = deg_n + N;                      // N   (zeroed)
  size_t zero_bytes = (size_t)(2 * G + 2 * E + 2 * N) * 4;
  float* fac_node = (float*)(cur_n + N);       // G
  float* fac_bond = fac_node + G;              // G
  float* recip_node = fac_bond + G;            // G
  int* off_e = (int*)(recip_node + G);         // E
  int* csr_e = off_e + E;                      // A
  int* off_n = csr_e + A;                      // N
  int* csr_n = off_n + N;                      // E
  int* bsum = csr_n + E;                       // 1024
  size_t off = ((size_t)((char*)(bsum + 1024) - ws) + 255) & ~(size_t)255;
  unsigned short* w1t_ba = (unsigned short*)(ws + off); off += (size_t)512 * 256 * 2;
  unsigned short* w2t_ba = (unsigned short*)(ws + off); off += (size_t)256 * 512 * 2;
  unsigned short* w1t_ab = (unsigned short*)(ws + off); off += (size_t)512 * 256 * 2;
  unsigned short* w2t_ab = (unsigned short*)(ws + off); off += (size_t)256 * 512 * 2;

  hipMemsetAsync(d_ws, 0, zero_bytes, stream);
  hipMemsetAsync(out_graph, 0, (size_t)G * HDIM * 4, stream);

  int wgrid = (256 * 512 + 255) / 256;
  cvtw_kernel<<<wgrid, 256, 0, stream>>>(ba_w1, w1t_ba, 256, 512);
  cvtw_kernel<<<wgrid, 256, 0, stream>>>(ba_w2, w2t_ba, 512, 256);
  cvtw_kernel<<<wgrid, 256, 0, stream>>>(ab_w1, w1t_ab, 256, 512);
  cvtw_kernel<<<wgrid, 256, 0, stream>>>(ab_w2, w2t_ab, 512, 256);

  count_kernel<<<(E + 255) / 256, 256, 0, stream>>>(node_gid, bond_gid, cnt_node, cnt_bond, N, E);
  factor_kernel<<<(G + 255) / 256, 256, 0, stream>>>(cnt_node, cnt_bond, fac_node, fac_bond,
                                                     recip_node, G);

  // ---- CSR for bond-angle graph ----
  deg_kernel<<<(A + 255) / 256, 256, 0, stream>>>(ba_dst, deg_e, A);
  int nbE = (E + 255) / 256;
  scan1_kernel<<<nbE, 256, 0, stream>>>(deg_e, off_e, bsum, E);
  scan2_kernel<<<1, 1024, 0, stream>>>(bsum, nbE);
  scan3_kernel<<<nbE, 256, 0, stream>>>(off_e, bsum, E);
  fill_kernel<<<(A + 255) / 256, 256, 0, stream>>>(ba_dst, off_e, cur_e, csr_e, A);

  angle_gather_kernel<<<(E + 3) / 4, 256, 0, stream>>>(bond_angle, ba_src, edge_hidden,
                                                       off_e, deg_e, csr_e, rbf_w, rbf_b,
                                                       out_edge, E);
  mlp_kernel<0><<<(E + 63) / 64, 512, 0, stream>>>(out_edge, out_edge, edge_hidden, bond_gid,
                                                   fac_bond, w1t_ba, ba_b1, w2t_ba, ba_b2,
                                                   ba_ln_g, ba_ln_b, nullptr, E);

  // ---- CSR for atom-bond graph ----
  deg_kernel<<<(E + 255) / 256, 256, 0, stream>>>(ab_dst, deg_n, E);
  int nbN = (N + 255) / 256;
  scan1_kernel<<<nbN, 256, 0, stream>>>(deg_n, off_n, bsum, N);
  scan2_kernel<<<1, 1024, 0, stream>>>(bsum, nbN);
  scan3_kernel<<<nbN, 256, 0, stream>>>(off_n, bsum, N);
  fill_kernel<<<(E + 255) / 256, 256, 0, stream>>>(ab_dst, off_n, cur_n, csr_n, E);

  node_gather_kernel<<<(N + 3) / 4, 256, 0, stream>>>(node_hidden, out_edge, ab_src,
                                                      off_n, deg_n, csr_n, out_node, N);
  mlp_kernel<1><<<(N + 63) / 64, 512, 0, stream>>>(out_node, out_node, node_hidden, node_gid,
                                                   fac_node, w1t_ab, ab_b1, w2t_ab, ab_b2,
                                                   ab_ln_g, ab_ln_b, out_graph, N);

  pooldiv_kernel<<<G, 256, 0, stream>>>(out_graph, recip_node);
}

// Round 2
// 839.380 us; speedup vs baseline: 1.0901x; 1.0901x over previous
//
#include <hip/hip_runtime.h>

#define HDIM 256
#define LNEPS 1e-5f

typedef float f32x4 __attribute__((ext_vector_type(4)));
typedef short bf16x8 __attribute__((ext_vector_type(8)));

static __device__ __forceinline__ unsigned short f2b(float f) {
  union { float f; unsigned u; } v; v.f = f;
  return (unsigned short)((v.u + 0x7fffu + ((v.u >> 16) & 1u)) >> 16);
}
static __device__ __forceinline__ unsigned pk2(float lo, float hi) {
  return (unsigned)f2b(lo) | ((unsigned)f2b(hi) << 16);
}

// ---------------- transpose + bf16 convert: in[K][N] -> out[N][K] ----------------
__global__ void cvtw_kernel(const float* __restrict__ in, unsigned short* __restrict__ out,
                            int K, int N) {
  int idx = blockIdx.x * 256 + threadIdx.x;
  if (idx >= K * N) return;
  int k = idx / N, n = idx - k * N;
  out[(size_t)n * K + k] = f2b(in[idx]);
}

// ---------------- per-graph counts ----------------
__global__ void count_kernel(const int* __restrict__ node_gid, const int* __restrict__ bond_gid,
                             int* cnt_node, int* cnt_bond, int N, int E) {
  int i = blockIdx.x * 256 + threadIdx.x;
  if (i < N) atomicAdd(&cnt_node[node_gid[i]], 1);
  if (i < E) atomicAdd(&cnt_bond[bond_gid[i]], 1);
}

__global__ void factor_kernel(const int* __restrict__ cnt_node, const int* __restrict__ cnt_bond,
                              float* fac_node, float* fac_bond, float* recip_node, int G) {
  int g = blockIdx.x * 256 + threadIdx.x;
  if (g >= G) return;
  float cn = fmaxf((float)cnt_node[g], 1.f);
  float cb = fmaxf((float)cnt_bond[g], 1.f);
  fac_node[g] = rsqrtf(cn);
  fac_bond[g] = rsqrtf(cb);
  recip_node[g] = 1.f / cn;
}

// ---------------- CSR build ----------------
__global__ void deg_kernel(const int* __restrict__ dst, int* __restrict__ deg, int n) {
  int i = blockIdx.x * 256 + threadIdx.x;
  if (i < n) atomicAdd(&deg[dst[i]], 1);
}

__global__ void scan1_kernel(const int* __restrict__ deg, int* __restrict__ excl,
                             int* __restrict__ bsum, int n) {
  int t = threadIdx.x;
  int i = blockIdx.x * 256 + t;
  int v = (i < n) ? deg[i] : 0;
  int lane = t & 63, w = t >> 6;
  int s = v;
#pragma unroll
  for (int d = 1; d < 64; d <<= 1) {
    int u = __shfl_up(s, d);
    if (lane >= d) s += u;
  }
  __shared__ int wsum[4];
  if (lane == 63) wsum[w] = s;
  __syncthreads();
  int base = 0;
  for (int ww = 0; ww < w; ++ww) base += wsum[ww];
  if (i < n) excl[i] = base + s - v;
  if (t == 255) bsum[blockIdx.x] = base + s;
}

__global__ void scan2_kernel(int* __restrict__ bsum, int nb) {
  int t = threadIdx.x;  // 1024 threads
  int v = (t < nb) ? bsum[t] : 0;
  int lane = t & 63, w = t >> 6;
  int s = v;
#pragma unroll
  for (int d = 1; d < 64; d <<= 1) {
    int u = __shfl_up(s, d);
    if (lane >= d) s += u;
  }
  __shared__ int wsum[16];
  if (lane == 63) wsum[w] = s;
  __syncthreads();
  int base = 0;
  for (int ww = 0; ww < w; ++ww) base += wsum[ww];
  if (t < nb) bsum[t] = base + s - v;
}

__global__ void scan3_kernel(int* __restrict__ excl, const int* __restrict__ bsum, int n) {
  int i = blockIdx.x * 256 + threadIdx.x;
  if (i < n) excl[i] += bsum[blockIdx.x];
}

__global__ void fill_kernel(const int* __restrict__ dst, const int* __restrict__ off,
                            int* __restrict__ cursor, int* __restrict__ csr, int n) {
  int i = blockIdx.x * 256 + threadIdx.x;
  if (i >= n) return;
  int d = dst[i];
  int p = atomicAdd(&cursor[d], 1);
  csr[off[d] + p] = i;
}

// ---------------- fused gather + MLP + LayerNorm + graph_normal + residual (+pool) ----
// 32 rows/block, 256 threads (4 waves) -> LDS 33.3KB -> 4 blocks/CU (vs 2 before):
// 4 independent barrier groups interleave their HBM phases (latency-bound fix).
// Gather is fused (no agg round-trip through HBM): each wave CSR-gathers 8 rows
// straight into the swizzled bf16 Xb tile. MODE 0: edge update (RBF + edge_hidden
// gather). MODE 1: node update (edge_out + node_hidden gather, with graph pool).
template <int MODE>
__global__ __launch_bounds__(256, 4) void fused_mlp_kernel(
    const float* __restrict__ hsrc,    // MODE0: edge_hidden ; MODE1: node_hidden
    const float* __restrict__ eextra,  // MODE0: bond_angle[A] ; MODE1: edge_out rows
    const int* __restrict__ srcidx,    // MODE0: ba_src ; MODE1: ab_src
    const int* __restrict__ off, const int* __restrict__ deg, const int* __restrict__ csr,
    const float* __restrict__ rbf_w, const float* __restrict__ rbf_b,
    const float* __restrict__ residual, const int* __restrict__ gid,
    const float* __restrict__ gfactor,
    const unsigned short* __restrict__ w1t, const float* __restrict__ b1,
    const unsigned short* __restrict__ w2t, const float* __restrict__ b2,
    const float* __restrict__ ln_g, const float* __restrict__ ln_b,
    float* __restrict__ out_rows, float* pool_out, int M) {
  __shared__ __align__(16) char smem[33280];
  char* Xb = smem;                        // bf16 [32][256] swizzled, 16KB
  char* Hb = smem + 16384;                // bf16 [32][256] (one half of H1), 16KB
  float* Outs = (float*)smem;             // f32 [32][256], overlays Xb+Hb after GEMMs
  float* fstat = (float*)(smem + 32768);  // [32][2] mean/rstd
  float* gfs = (float*)(smem + 33024);    // [32]
  int* gid_s = (int*)(smem + 33152);      // [32]

  int t = threadIdx.x;
  int row0 = blockIdx.x * 32;
  int w = t >> 6, lane = t & 63;
  int l15 = lane & 15, lg = lane >> 4;

  // ---- fused gather: build Xb rows (wave w owns rows w*8..w*8+7) ----
  {
    int c4 = lane * 4;
    if (t < 32) {
      int r = row0 + t;
      int g = (r < M) ? gid[r] : 0;
      gid_s[t] = g;
      gfs[t] = gfactor[g];
    }
    for (int i = 0; i < 8; ++i) {
      int r = w * 8 + i;
      int d = row0 + r;
      f32x4 acc = (f32x4)0.f;
      if (d < M) {
        int start = off[d], cnt = deg[d];
        if (MODE == 0) {
          float rbfs = 0.f;
          float cc = 0.1f * (float)(lane & 31);
          for (int j = 0; j < cnt; ++j) {
            int a = csr[start + j];
            float av = eextra[a];
            if (lane < 32) {
              float dd = av - cc;
              rbfs += __expf(-10.f * dd * dd);
            }
            int s = srcidx[a];
            acc += *(const f32x4*)&hsrc[(size_t)s * HDIM + c4];
          }
#pragma unroll
          for (int k = 0; k < 32; ++k) {
            float rv = __shfl(rbfs, k);
            f32x4 wv = *(const f32x4*)&rbf_w[k * HDIM + c4];
            acc[0] += rv * wv[0]; acc[1] += rv * wv[1];
            acc[2] += rv * wv[2]; acc[3] += rv * wv[3];
          }
          f32x4 bv = *(const f32x4*)&rbf_b[c4];
          float fc = (float)cnt;
          acc[0] += fc * bv[0]; acc[1] += fc * bv[1];
          acc[2] += fc * bv[2]; acc[3] += fc * bv[3];
        } else {
          for (int j = 0; j < cnt; ++j) {
            int e = csr[start + j];
            int s = srcidx[e];
            f32x4 ev = *(const f32x4*)&eextra[(size_t)e * HDIM + c4];
            f32x4 nv = *(const f32x4*)&hsrc[(size_t)s * HDIM + c4];
            acc += ev;
            acc += nv;
          }
        }
      }
      int byte = (r * 512 + lane * 8) ^ ((r & 7) << 4);
      *(uint2*)(Xb + byte) = make_uint2(pk2(acc[0], acc[1]), pk2(acc[2], acc[3]));
    }
  }
  __syncthreads();

  f32x4 acc2[2][4];  // [mt][nf] : row m = mt*16 + lg*4 + jr ; col n2 = w*64 + nf*16 + l15
#pragma unroll
  for (int mt = 0; mt < 2; ++mt)
#pragma unroll
    for (int nf = 0; nf < 4; ++nf) acc2[mt][nf] = (f32x4)0.f;

  for (int h = 0; h < 2; ++h) {
    // ---- GEMM1 (swapped): D[n1][m]; wave's n1 tiles = h*256 + w*64 + tt*16 ----
    f32x4 acc1[4][2];
#pragma unroll
    for (int tt = 0; tt < 4; ++tt)
#pragma unroll
      for (int mt = 0; mt < 2; ++mt) acc1[tt][mt] = (f32x4)0.f;

    const unsigned short* a1p = w1t + (size_t)(h * 256 + w * 64 + l15) * 256 + lg * 8;
#pragma unroll
    for (int kk = 0; kk < 8; ++kk) {
      bf16x8 xfr[2];
#pragma unroll
      for (int mt = 0; mt < 2; ++mt) {
        int m = mt * 16 + l15;
        int byte = (m * 512 + kk * 64 + lg * 16) ^ ((m & 7) << 4);
        xfr[mt] = *(const bf16x8*)(Xb + byte);
      }
#pragma unroll
      for (int tt = 0; tt < 4; ++tt) {
        bf16x8 afr = *(const bf16x8*)(a1p + tt * 16 * 256 + kk * 32);
#pragma unroll
        for (int mt = 0; mt < 2; ++mt)
          acc1[tt][mt] = __builtin_amdgcn_mfma_f32_16x16x32_bf16(afr, xfr[mt], acc1[tt][mt], 0, 0, 0);
      }
    }

    // ---- bias + relu + packed H1 store: H1[m][n1], n1 = w*64 + tt*16 + lg*4 + r ----
#pragma unroll
    for (int tt = 0; tt < 4; ++tt) {
      f32x4 b1v = *(const f32x4*)&b1[h * 256 + w * 64 + tt * 16 + lg * 4];
#pragma unroll
      for (int mt = 0; mt < 2; ++mt) {
        f32x4 v = acc1[tt][mt] + b1v;
        v[0] = fmaxf(v[0], 0.f); v[1] = fmaxf(v[1], 0.f);
        v[2] = fmaxf(v[2], 0.f); v[3] = fmaxf(v[3], 0.f);
        int m = mt * 16 + l15;
        int n1 = w * 64 + tt * 16 + lg * 4;  // within this half
        int byte = (m * 512 + n1 * 2) ^ ((m & 7) << 4);
        *(uint2*)(Hb + byte) = make_uint2(pk2(v[0], v[1]), pk2(v[2], v[3]));
      }
    }
    __syncthreads();

    // ---- GEMM2 partial: A = H1 rows (LDS), B = w2t cols (L2) ----
    const unsigned short* w2p = w2t + (size_t)(w * 64 + l15) * 512 + h * 256 + lg * 8;
#pragma unroll
    for (int kk = 0; kk < 8; ++kk) {
      bf16x8 hfr[2];
#pragma unroll
      for (int mt = 0; mt < 2; ++mt) {
        int m = mt * 16 + l15;
        int byte = (m * 512 + kk * 64 + lg * 16) ^ ((m & 7) << 4);
        hfr[mt] = *(const bf16x8*)(Hb + byte);
      }
#pragma unroll
      for (int nf = 0; nf < 4; ++nf) {
        bf16x8 wfr = *(const bf16x8*)(w2p + nf * 16 * 512 + kk * 32);
#pragma unroll
        for (int mt = 0; mt < 2; ++mt)
          acc2[mt][nf] = __builtin_amdgcn_mfma_f32_16x16x32_bf16(hfr[mt], wfr, acc2[mt][nf], 0, 0, 0);
      }
    }
    __syncthreads();
  }

  // ---- Outs = acc2 + b2 (f32 LDS) ----
#pragma unroll
  for (int nf = 0; nf < 4; ++nf) {
    float b2v = b2[w * 64 + nf * 16 + l15];
#pragma unroll
    for (int mt = 0; mt < 2; ++mt)
#pragma unroll
      for (int jr = 0; jr < 4; ++jr)
        Outs[(mt * 16 + lg * 4 + jr) * 256 + (w * 64 + nf * 16 + l15)] = acc2[mt][nf][jr] + b2v;
  }
  __syncthreads();

  // ---- LayerNorm stats: 8 threads per row ----
  {
    int row = t >> 3, sub = t & 7;
    float s = 0.f, ss = 0.f;
#pragma unroll
    for (int i = 0; i < 8; ++i) {
      f32x4 v = *(const f32x4*)&Outs[row * 256 + sub * 32 + i * 4];
      s += v[0] + v[1] + v[2] + v[3];
      ss += v[0] * v[0] + v[1] * v[1] + v[2] * v[2] + v[3] * v[3];
    }
    s += __shfl_xor(s, 1); ss += __shfl_xor(ss, 1);
    s += __shfl_xor(s, 2); ss += __shfl_xor(ss, 2);
    s += __shfl_xor(s, 4); ss += __shfl_xor(ss, 4);
    if (sub == 0) {
      float mean = s * (1.f / 256.f);
      float var = ss * (1.f / 256.f) - mean * mean;
      fstat[row * 2] = mean;
      fstat[row * 2 + 1] = rsqrtf(var + LNEPS);
    }
  }
  __syncthreads();

  // ---- finalize: LN affine, graph_normal, residual, store (+segmented pool) ----
  {
    float g_t = ln_g[t], bb_t = ln_b[t];
    float psum = 0.f;
    int curg = -1;
    for (int p = 0; p < 32; ++p) {
      int gr = row0 + p;
      if (gr < M) {
        float v = Outs[p * 256 + t];
        v = (v - fstat[p * 2]) * fstat[p * 2 + 1] * g_t + bb_t;
        v *= gfs[p];
        v += residual[(size_t)gr * HDIM + t];
        out_rows[(size_t)gr * HDIM + t] = v;
        if (MODE == 1) {
          int g = gid_s[p];
          if (g != curg) {
            if (curg >= 0) atomicAdd(&pool_out[(size_t)curg * HDIM + t], psum);
            psum = 0.f;
            curg = g;
          }
          psum += v;
        }
      }
    }
    if (MODE == 1 && curg >= 0) atomicAdd(&pool_out[(size_t)curg * HDIM + t], psum);
  }
}

// ---------------- pooled sums -> means ----------------
__global__ void pooldiv_kernel(float* out_graph, const float* __restrict__ recip_node) {
  int g = blockIdx.x, t = threadIdx.x;
  out_graph[(size_t)g * HDIM + t] *= recip_node[g];
}

extern "C" void kernel_launch(void* const* d_in, const int* in_sizes, int n_in,
                              void* d_out, int out_size, void* d_ws, size_t ws_size,
                              hipStream_t stream) {
  const float* node_hidden = (const float*)d_in[0];
  const float* edge_hidden = (const float*)d_in[1];
  const float* bond_angle = (const float*)d_in[2];
  const int* ab_src = (const int*)d_in[3];
  const int* ab_dst = (const int*)d_in[4];
  const int* ba_src = (const int*)d_in[5];
  const int* ba_dst = (const int*)d_in[6];
  const int* node_gid = (const int*)d_in[7];
  const int* bond_gid = (const int*)d_in[8];
  const float* rbf_w = (const float*)d_in[10];
  const float* rbf_b = (const float*)d_in[11];
  const float* ba_w1 = (const float*)d_in[12];
  const float* ba_b1 = (const float*)d_in[13];
  const float* ba_w2 = (const float*)d_in[14];
  const float* ba_b2 = (const float*)d_in[15];
  const float* ba_ln_g = (const float*)d_in[16];
  const float* ba_ln_b = (const float*)d_in[17];
  const float* ab_w1 = (const float*)d_in[18];
  const float* ab_b1 = (const float*)d_in[19];
  const float* ab_w2 = (const float*)d_in[20];
  const float* ab_b2 = (const float*)d_in[21];
  const float* ab_ln_g = (const float*)d_in[22];
  const float* ab_ln_b = (const float*)d_in[23];

  int N = in_sizes[0] / HDIM;
  int E = in_sizes[1] / HDIM;
  int A = in_sizes[2];
  int G = out_size / HDIM - N - E;

  float* out_node = (float*)d_out;
  float* out_edge = out_node + (size_t)N * HDIM;
  float* out_graph = out_edge + (size_t)E * HDIM;

  // ---- workspace layout ----
  char* ws = (char*)d_ws;
  int* cnt_node = (int*)ws;                    // G   (zeroed)
  int* cnt_bond = cnt_node + G;                // G   (zeroed)
  int* deg_e = cnt_bond + G;                   // E   (zeroed)
  int* cur_e = deg_e + E;                      // E   (zeroed)
  int* deg_n = cur_e + E;                      // N   (zeroed)
  int* cur_n = deg_n + N;                      // N   (zeroed)
  size_t zero_bytes = (size_t)(2 * G + 2 * E + 2 * N) * 4;
  float* fac_node = (float*)(cur_n + N);       // G
  float* fac_bond = fac_node + G;              // G
  float* recip_node = fac_bond + G;            // G
  int* off_e = (int*)(recip_node + G);         // E
  int* csr_e = off_e + E;                      // A
  int* off_n = csr_e + A;                      // N
  int* csr_n = off_n + N;                      // E
  int* bsum = csr_n + E;                       // 1024
  size_t off = ((size_t)((char*)(bsum + 1024) - ws) + 255) & ~(size_t)255;
  unsigned short* w1t_ba = (unsigned short*)(ws + off); off += (size_t)512 * 256 * 2;
  unsigned short* w2t_ba = (unsigned short*)(ws + off); off += (size_t)256 * 512 * 2;
  unsigned short* w1t_ab = (unsigned short*)(ws + off); off += (size_t)512 * 256 * 2;
  unsigned short* w2t_ab = (unsigned short*)(ws + off); off += (size_t)256 * 512 * 2;

  hipMemsetAsync(d_ws, 0, zero_bytes, stream);
  hipMemsetAsync(out_graph, 0, (size_t)G * HDIM * 4, stream);

  int wgrid = (256 * 512 + 255) / 256;
  cvtw_kernel<<<wgrid, 256, 0, stream>>>(ba_w1, w1t_ba, 256, 512);
  cvtw_kernel<<<wgrid, 256, 0, stream>>>(ba_w2, w2t_ba, 512, 256);
  cvtw_kernel<<<wgrid, 256, 0, stream>>>(ab_w1, w1t_ab, 256, 512);
  cvtw_kernel<<<wgrid, 256, 0, stream>>>(ab_w2, w2t_ab, 512, 256);

  count_kernel<<<(E + 255) / 256, 256, 0, stream>>>(node_gid, bond_gid, cnt_node, cnt_bond, N, E);
  factor_kernel<<<(G + 255) / 256, 256, 0, stream>>>(cnt_node, cnt_bond, fac_node, fac_bond,
                                                     recip_node, G);

  // ---- CSR for bond-angle graph ----
  deg_kernel<<<(A + 255) / 256, 256, 0, stream>>>(ba_dst, deg_e, A);
  int nbE = (E + 255) / 256;
  scan1_kernel<<<nbE, 256, 0, stream>>>(deg_e, off_e, bsum, E);
  scan2_kernel<<<1, 1024, 0, stream>>>(bsum, nbE);
  scan3_kernel<<<nbE, 256, 0, stream>>>(off_e, bsum, E);
  fill_kernel<<<(A + 255) / 256, 256, 0, stream>>>(ba_dst, off_e, cur_e, csr_e, A);

  // ---- fused gather + MLP for bond features ----
  fused_mlp_kernel<0><<<(E + 31) / 32, 256, 0, stream>>>(
      edge_hidden, bond_angle, ba_src, off_e, deg_e, csr_e, rbf_w, rbf_b,
      edge_hidden, bond_gid, fac_bond, w1t_ba, ba_b1, w2t_ba, ba_b2,
      ba_ln_g, ba_ln_b, out_edge, nullptr, E);

  // ---- CSR for atom-bond graph ----
  deg_kernel<<<(E + 255) / 256, 256, 0, stream>>>(ab_dst, deg_n, E);
  int nbN = (N + 255) / 256;
  scan1_kernel<<<nbN, 256, 0, stream>>>(deg_n, off_n, bsum, N);
  scan2_kernel<<<1, 1024, 0, stream>>>(bsum, nbN);
  scan3_kernel<<<nbN, 256, 0, stream>>>(off_n, bsum, N);
  fill_kernel<<<(E + 255) / 256, 256, 0, stream>>>(ab_dst, off_n, cur_n, csr_n, E);

  // ---- fused gather + MLP for atom features (+pool) ----
  fused_mlp_kernel<1><<<(N + 31) / 32, 256, 0, stream>>>(
      node_hidden, out_edge, ab_src, off_n, deg_n, csr_n, nullptr, nullptr,
      node_hidden, node_gid, fac_node, w1t_ab, ab_b1, w2t_ab, ab_b2,
      ab_ln_g, ab_ln_b, out_node, out_graph, N);

  pooldiv_kernel<<<G, 256, 0, stream>>>(out_graph, recip_node);
}